// Round 5
// baseline (68.711 us; speedup 1.0000x reference)
//
#include <hip/hip_runtime.h>

#define B 32
#define N 1024
#define D 256
#define H 8
#define E 256
#define HE 2048
#define NCH 16   // k_attn n-chunks

// d_ws float offsets
#define OFF_XBAR  0         // [B][D]            8192
#define OFF_KBAR  8192      // [B][HE]           65536
#define OFF_U     73728     // [B][H][D]         65536 (scale folded)
#define OFF_VPART 139264    // [B][NCH][H][D]    1048576
#define OFF_ZPART 1187840   // [B][NCH][H]       4096
#define OFF_VBAR  1191936   // [B][H][D]         65536 (normalized by 1/Z)
#define OFF_RES   1257472   // [B][HE]           65536

#define DOT4(a, v) ((a).x * (v).x + (a).y * (v).y + (a).z * (v).z + (a).w * (v).w)

// ---- xbar[b,d] = sum_n wsum[n]*x[b,n,d]
__global__ __launch_bounds__(256) void k_xbar(const float4* __restrict__ x4,
                                              const float* __restrict__ wsum,
                                              float4* __restrict__ Xbar4) {
    __shared__ float4 ps[32][8];
    int t = threadIdx.x, b = blockIdx.x, dc = blockIdx.y;
    int dq = t & 7, rep = t >> 3;
    float4 acc = make_float4(0.f, 0.f, 0.f, 0.f);
#pragma unroll 4
    for (int i = 0; i < 32; ++i) {
        int n = i * 32 + rep;
        float w = wsum[n];
        float4 xv = x4[(size_t)(b * N + n) * 64 + dc * 8 + dq];
        acc.x += w * xv.x; acc.y += w * xv.y; acc.z += w * xv.z; acc.w += w * xv.w;
    }
    ps[rep][dq] = acc;
    __syncthreads();
    if (t < 8) {
        float4 s = make_float4(0.f, 0.f, 0.f, 0.f);
#pragma unroll
        for (int r = 0; r < 32; ++r) {
            float4 v = ps[r][t];
            s.x += v.x; s.y += v.y; s.z += v.z; s.w += v.w;
        }
        Xbar4[b * 64 + dc * 8 + t] = s;
    }
}

// ---- Kbar[b,he] = Wk[he,:].xbar[b,:] + S*bk[he]
__global__ __launch_bounds__(256) void k_kbar(const float4* __restrict__ Wk4,
                                              const float* __restrict__ bk,
                                              const float* __restrict__ wsum,
                                              const float4* __restrict__ Xbar4,
                                              float* __restrict__ Kbar) {
    __shared__ float Xs[32][260];
    __shared__ float Wks[8][260];
    __shared__ float red[256];
    int t = threadIdx.x, he0 = blockIdx.x * 8;
    red[t] = wsum[t] + wsum[t + 256] + wsum[t + 512] + wsum[t + 768];
#pragma unroll
    for (int j = 0; j < 8; ++j) {
        int i4 = t + j * 256, r = i4 >> 6, c = i4 & 63;
        *(float4*)&Xs[r][c * 4] = Xbar4[r * 64 + c];
    }
#pragma unroll
    for (int j = 0; j < 2; ++j) {
        int i4 = t + j * 256, r = i4 >> 6, c = i4 & 63;
        *(float4*)&Wks[r][c * 4] = Wk4[(size_t)(he0 + r) * 64 + c];
    }
    __syncthreads();
    for (int s = 128; s > 0; s >>= 1) {
        if (t < s) red[t] += red[t + s];
        __syncthreads();
    }
    float S = red[0];
    int bb = t & 31, rr = t >> 5;
    float a = 0.f;
#pragma unroll 4
    for (int c = 0; c < 64; ++c) {
        float4 xv = *(float4*)&Xs[bb][c * 4];
        float4 w = *(float4*)&Wks[rr][c * 4];
        a += DOT4(w, xv);
    }
    Kbar[(size_t)bb * HE + he0 + rr] = a + S * bk[he0 + rr];
}

// ---- U[b,h,d] = scale * sum_e Wq[h*E+e,d] * Kbar[b,h*E+e]
// grid (H, 4 b-groups, 2 d-halves); no atomics, no memset.
__global__ __launch_bounds__(256) void k_u(const float4* __restrict__ Wq4,
                                           const float* __restrict__ Kbar,
                                           float* __restrict__ U) {
    __shared__ float psv[256 * 33];   // (eg*32+dq)*33 + j*4 + c
    int t = threadIdx.x, h = blockIdx.x, bg = blockIdx.y, dh = blockIdx.z;
    int dq = t & 31, eg = t >> 5;
    float4 acc[8];
#pragma unroll
    for (int j = 0; j < 8; ++j) acc[j] = make_float4(0.f, 0.f, 0.f, 0.f);
    for (int i = 0; i < 32; ++i) {
        int e = eg * 32 + i;
        float4 wq = Wq4[(size_t)(h * E + e) * 64 + dh * 32 + dq];
#pragma unroll
        for (int j = 0; j < 8; ++j) {
            float kb = Kbar[(size_t)(bg * 8 + j) * HE + h * E + e];
            acc[j].x += kb * wq.x; acc[j].y += kb * wq.y;
            acc[j].z += kb * wq.z; acc[j].w += kb * wq.w;
        }
    }
#pragma unroll
    for (int j = 0; j < 8; ++j) {
        int base = (eg * 32 + dq) * 33 + j * 4;
        psv[base + 0] = acc[j].x; psv[base + 1] = acc[j].y;
        psv[base + 2] = acc[j].z; psv[base + 3] = acc[j].w;
    }
    __syncthreads();
    int dq2 = t & 31, j2 = t >> 5;
    float4 s = make_float4(0.f, 0.f, 0.f, 0.f);
#pragma unroll
    for (int eg2 = 0; eg2 < 8; ++eg2) {
        int base = (eg2 * 32 + dq2) * 33 + j2 * 4;
        s.x += psv[base]; s.y += psv[base + 1]; s.z += psv[base + 2]; s.w += psv[base + 3];
    }
    s.x *= 0.0625f; s.y *= 0.0625f; s.z *= 0.0625f; s.w *= 0.0625f;
    *(float4*)&U[((size_t)(bg * 8 + j2) * H + h) * D + dh * 128 + dq2 * 4] = s;
}

// ---- fused attention: per row, logits + exp + weighted-x accumulate, all in registers.
// grid (B, NCH); 4 waves/block, 16 rows/wave; x read ONCE, coalesced.
__global__ __launch_bounds__(256) void k_attn(const float4* __restrict__ x4,
                                              const float* __restrict__ U,
                                              float* __restrict__ Vpart,
                                              float* __restrict__ Zpart) {
    __shared__ float psv[4 * 64 * 33];   // 33.8 KB
    __shared__ float zred[4][8];
    int t = threadIdx.x, b = blockIdx.x, cch = blockIdx.y;
    int lane = t & 63, w = t >> 6;
    const float* ub = U + (size_t)b * HE;
    float4 u4[8];
#pragma unroll
    for (int h = 0; h < 8; ++h) u4[h] = *(const float4*)&ub[h * D + lane * 4];
    float4 accV[8];
    float zacc[8];
#pragma unroll
    for (int h = 0; h < 8; ++h) { accV[h] = make_float4(0.f, 0.f, 0.f, 0.f); zacc[h] = 0.f; }
    int n0 = cch * 64 + w * 16;
    const float4* xrow = x4 + ((size_t)b * N + n0) * 64 + lane;
    for (int i = 0; i < 16; i += 2) {
        float4 xa = xrow[(size_t)i * 64];
        float4 xc = xrow[(size_t)(i + 1) * 64];
        float pa[8], pc[8];
#pragma unroll
        for (int h = 0; h < 8; ++h) { pa[h] = DOT4(xa, u4[h]); pc[h] = DOT4(xc, u4[h]); }
#pragma unroll
        for (int off = 32; off > 0; off >>= 1) {
#pragma unroll
            for (int h = 0; h < 8; ++h) {
                pa[h] += __shfl_xor(pa[h], off);
                pc[h] += __shfl_xor(pc[h], off);
            }
        }
#pragma unroll
        for (int h = 0; h < 8; ++h) {
            float za = __expf(pa[h]), zc = __expf(pc[h]);   // logits tiny; no max-sub needed
            zacc[h] += za + zc;
            accV[h].x += za * xa.x + zc * xc.x;
            accV[h].y += za * xa.y + zc * xc.y;
            accV[h].z += za * xa.z + zc * xc.z;
            accV[h].w += za * xa.w + zc * xc.w;
        }
    }
    // 4-wave combine
#pragma unroll
    for (int h = 0; h < 8; ++h) {
        int base = (w * 64 + lane) * 33 + h * 4;
        psv[base + 0] = accV[h].x; psv[base + 1] = accV[h].y;
        psv[base + 2] = accV[h].z; psv[base + 3] = accV[h].w;
    }
    if (lane == 0) {
#pragma unroll
        for (int h = 0; h < 8; ++h) zred[w][h] = zacc[h];
    }
    __syncthreads();
#pragma unroll
    for (int k = 0; k < 2; ++k) {
        int item = t + k * 256;
        int dq = item & 63, h = item >> 6;
        float4 v = make_float4(0.f, 0.f, 0.f, 0.f);
#pragma unroll
        for (int ww = 0; ww < 4; ++ww) {
            int base = (ww * 64 + dq) * 33 + h * 4;
            v.x += psv[base]; v.y += psv[base + 1]; v.z += psv[base + 2]; v.w += psv[base + 3];
        }
        *(float4*)&Vpart[(((size_t)(b * NCH + cch) * H + h) * 64 + dq) * 4] = v;
    }
    if (t < 8) {
        float z = zred[0][t] + zred[1][t] + zred[2][t] + zred[3][t];
        Zpart[((size_t)b * NCH + cch) * H + t] = z;
    }
}

// ---- Vbar[b,h,:] = (sum_c Vpart[b,c,h,:]) / Z[b,h]
__global__ __launch_bounds__(256) void k_vred(const float4* __restrict__ Vp4,
                                              const float* __restrict__ Zpart,
                                              float4* __restrict__ Vbar4) {
    int g = blockIdx.x * 256 + threadIdx.x;   // 16384 items
    int dq = g & 63, h = (g >> 6) & 7, b = g >> 9;
    float4 s = make_float4(0.f, 0.f, 0.f, 0.f);
    float zs = 0.f;
#pragma unroll
    for (int c = 0; c < NCH; ++c) {
        float4 v = Vp4[((size_t)(b * NCH + c) * H + h) * 64 + dq];
        s.x += v.x; s.y += v.y; s.z += v.z; s.w += v.w;
        zs += Zpart[((size_t)b * NCH + c) * H + h];
    }
    float inv = 1.0f / zs;
    s.x *= inv; s.y *= inv; s.z *= inv; s.w *= inv;
    Vbar4[(size_t)(b * H + h) * 64 + dq] = s;
}

// ---- res[b,he] = Wv[he,:].vbar[b,h,:] + bv[he]
__global__ __launch_bounds__(256) void k_result(const float4* __restrict__ Wv4,
                                                const float* __restrict__ bv,
                                                const float4* __restrict__ Vbar4,
                                                float* __restrict__ res) {
    __shared__ float Vs[32][260];
    __shared__ float Ws[16][260];
    int t = threadIdx.x, h = blockIdx.x;
    int he0 = h * E + blockIdx.y * 16;
#pragma unroll
    for (int j = 0; j < 8; ++j) {
        int i4 = t + j * 256, r = i4 >> 6, c = i4 & 63;
        *(float4*)&Vs[r][c * 4] = Vbar4[(size_t)(r * H + h) * 64 + c];
    }
#pragma unroll
    for (int j = 0; j < 4; ++j) {
        int i4 = t + j * 256, r = i4 >> 6, c = i4 & 63;
        *(float4*)&Ws[r][c * 4] = Wv4[(size_t)(he0 + r) * 64 + c];
    }
    __syncthreads();
    int bb = t & 31, rr = t >> 5;
    float a0 = 0.f, a1 = 0.f;
#pragma unroll 4
    for (int c = 0; c < 64; ++c) {
        float4 xv = *(float4*)&Vs[bb][c * 4];
        float4 w0 = *(float4*)&Ws[rr][c * 4];
        float4 w1 = *(float4*)&Ws[rr + 8][c * 4];
        a0 += DOT4(w0, xv);
        a1 += DOT4(w1, xv);
    }
    res[(size_t)bb * HE + he0 + rr] = a0 + bv[he0 + rr];
    res[(size_t)bb * HE + he0 + rr + 8] = a1 + bv[he0 + rr + 8];
}

// ---- out[b,d] += Wo[d,kslice].res[b,kslice] (+bo)
__global__ __launch_bounds__(256) void k_out(const float4* __restrict__ Wo4,
                                             const float* __restrict__ bo,
                                             const float4* __restrict__ res4,
                                             float* __restrict__ out) {
    __shared__ float Rs[32][260];
    __shared__ float Ws[8][260];
    int t = threadIdx.x, d0 = blockIdx.x * 8;
    int k4 = blockIdx.y * 64;
#pragma unroll
    for (int j = 0; j < 8; ++j) {
        int i4 = t + j * 256, r = i4 >> 6, c = i4 & 63;
        *(float4*)&Rs[r][c * 4] = res4[(size_t)r * 512 + k4 + c];
    }
#pragma unroll
    for (int j = 0; j < 2; ++j) {
        int i4 = t + j * 256, r = i4 >> 6, c = i4 & 63;
        *(float4*)&Ws[r][c * 4] = Wo4[(size_t)(d0 + r) * 512 + k4 + c];
    }
    __syncthreads();
    int bb = t & 31, rr = t >> 5;
    float a = 0.f;
#pragma unroll 4
    for (int c = 0; c < 64; ++c) {
        float4 w = *(float4*)&Ws[rr][c * 4];
        float4 rv = *(float4*)&Rs[bb][c * 4];
        a += DOT4(w, rv);
    }
    if (blockIdx.y == 0) a += bo[d0 + rr];
    atomicAdd(&out[(size_t)bb * D + d0 + rr], a);
}

extern "C" void kernel_launch(void* const* d_in, const int* in_sizes, int n_in,
                              void* d_out, int out_size, void* d_ws, size_t ws_size,
                              hipStream_t stream) {
    const float* x    = (const float*)d_in[0];
    const float* Wq   = (const float*)d_in[1];
    // d_in[2] = bq : softmax-invariant, drops out
    const float* Wk   = (const float*)d_in[3];
    const float* bk   = (const float*)d_in[4];
    const float* Wv   = (const float*)d_in[5];
    const float* bv   = (const float*)d_in[6];
    const float* wsum = (const float*)d_in[7];
    // d_in[8] = bs : softmax-invariant, drops out
    const float* Wo   = (const float*)d_in[9];
    const float* bo   = (const float*)d_in[10];
    float* wsf   = (float*)d_ws;
    float* XBAR  = wsf + OFF_XBAR;
    float* KBAR  = wsf + OFF_KBAR;
    float* U     = wsf + OFF_U;
    float* VPART = wsf + OFF_VPART;
    float* ZPART = wsf + OFF_ZPART;
    float* VBAR  = wsf + OFF_VBAR;
    float* RES   = wsf + OFF_RES;

    hipMemsetAsync(d_out, 0, (size_t)B * D * 4, stream);

    k_xbar<<<dim3(B, 8), 256, 0, stream>>>((const float4*)x, wsum, (float4*)XBAR);
    k_kbar<<<256, 256, 0, stream>>>((const float4*)Wk, bk, wsum, (const float4*)XBAR, KBAR);
    k_u<<<dim3(H, 4, 2), 256, 0, stream>>>((const float4*)Wq, KBAR, U);
    k_attn<<<dim3(B, NCH), 256, 0, stream>>>((const float4*)x, U, VPART, ZPART);
    k_vred<<<64, 256, 0, stream>>>((const float4*)VPART, ZPART, (float4*)VBAR);
    k_result<<<dim3(H, 16), 256, 0, stream>>>((const float4*)Wv, bv, (const float4*)VBAR, RES);
    k_out<<<dim3(32, 8), 256, 0, stream>>>((const float4*)Wo, bo, (const float4*)RES, (float*)d_out);
}